// Round 5
// baseline (554.651 us; speedup 1.0000x reference)
//
#include <hip/hip_runtime.h>
#include <math.h>

#define KS 48
#define TLEN 512
#define BN 1024
#define START_S 46
#define STOP_S 47
#define NEGV -10000.0f
#define PF 8   // emission prefetch depth

typedef float v2f __attribute__((ext_vector_type(2)));

__device__ __forceinline__ float bcast_lane0(float v) {
    return __builtin_bit_cast(float, __builtin_amdgcn_readfirstlane(__builtin_bit_cast(int, v)));
}

// One wave per sequence; fwd + vit chains fused for 2-chain ILP (no fwd/vit tail,
// emissions loaded once, one barrier covers both chains' LDS round trips).
__global__ __launch_bounds__(64) void crf_fused(
    const float* __restrict__ feats,   // [B, T, K]
    const float* __restrict__ trans,   // [K, K]  trans[next, prev]
    const int*   __restrict__ tags,    // [B, T]
    float*       __restrict__ out)     // [B] nll | [B] path_score | [B*T] paths
{
    const int b    = blockIdx.x;
    const int lane = threadIdx.x;
    const bool act = lane < KS;

    __shared__ float ubuf[2][64];                // fwd exp(alpha - s), dbuf
    __shared__ float wbuf[2][64];                // vit values, dbuf
    __shared__ unsigned char bp_sh[TLEN][KS];    // backpointers (24 KB)
    __shared__ unsigned char path_sh[TLEN];

    const float* fb = feats + (size_t)b * TLEN * KS;
    const int*   tb = tags + (size_t)b * TLEN;

    // per-lane masked transition row (lane = next state)
    float Trow[KS];   // masked trans[next=lane][p] — reference's exact add
    float Erow[KS];   // exp(masked) ; exp(-10000)==0 masks for free
    {
        const float* tr = trans + (act ? lane : 0) * KS;
        #pragma unroll
        for (int p = 0; p < KS; ++p) {
            float tv = act ? tr[p] : NEGV;
            if (lane == START_S) tv = NEGV;
            if (p == STOP_S)     tv = NEGV;
            Trow[p] = tv;
            Erow[p] = __expf(tv);
        }
    }
    float tstart = act ? trans[lane * KS + START_S] : NEGV;
    if (lane == START_S) tstart = NEGV;

    float alpha;                                     // fwd state
    float vit = (lane == START_S) ? 0.0f : NEGV;     // vit state

    // ---- combined step: advances BOTH chains with one emission + one barrier ----
    auto cstep = [&](float emv, int t) {
        float s  = bcast_lane0(alpha);           // lane-0 alpha finite -> valid LSE shift
        float ue = __expf(alpha - s);            // -inf lanes -> 0
        const int bsel = t & 1;
        ubuf[bsel][lane] = ue;
        wbuf[bsel][lane] = vit;
        __syncthreads();                         // 1-wave block: cheap
        const float4* uu = (const float4*)ubuf[bsel];
        const float4* ww = (const float4*)wbuf[bsel];

        v2f acc0 = {0.f, 0.f}, acc1 = {0.f, 0.f};
        float bs[12]; int ib[12];
        #pragma unroll
        for (int g = 0; g < KS / 4; ++g) {
            float4 u = uu[g];
            float4 w = ww[g];
            v2f ea = {Erow[4 * g + 0], Erow[4 * g + 1]};
            v2f eb = {Erow[4 * g + 2], Erow[4 * g + 3]};
            v2f ta = {Trow[4 * g + 0], Trow[4 * g + 1]};
            v2f tc = {Trow[4 * g + 2], Trow[4 * g + 3]};
            v2f ua = {u.x, u.y}, ub = {u.z, u.w};
            v2f wa = {w.x, w.y}, wb = {w.z, w.w};
            acc0 = __builtin_elementwise_fma(ua, ea, acc0);      // v_pk_fma_f32
            acc1 = __builtin_elementwise_fma(ub, eb, acc1);
            v2f sa = wa + ta;                                    // v_pk_add_f32
            v2f sb = wb + tc;
            float m01 = fmaxf(sa.x, sa.y); int i01 = (sa.y > sa.x) ? 4 * g + 1 : 4 * g + 0;
            float m23 = fmaxf(sb.x, sb.y); int i23 = (sb.y > sb.x) ? 4 * g + 3 : 4 * g + 2;
            bs[g] = fmaxf(m01, m23);       ib[g] = (m23 > m01) ? i23 : i01;
        }
        #pragma unroll
        for (int st = 0; st < 6; ++st) {   // 12 -> 6
            float a = bs[2 * st], c2 = bs[2 * st + 1];
            int ia = ib[2 * st], ic = ib[2 * st + 1];
            bs[st] = fmaxf(a, c2); ib[st] = (c2 > a) ? ic : ia;
        }
        #pragma unroll
        for (int st = 0; st < 3; ++st) {   // 6 -> 3
            float a = bs[2 * st], c2 = bs[2 * st + 1];
            int ia = ib[2 * st], ic = ib[2 * st + 1];
            bs[st] = fmaxf(a, c2); ib[st] = (c2 > a) ? ic : ia;
        }
        float best = fmaxf(bs[0], bs[1]);
        int   bi   = (bs[1] > bs[0]) ? ib[1] : ib[0];
        bi   = (bs[2] > best) ? ib[2] : bi;
        best = fmaxf(best, bs[2]);

        alpha = emv + s + __logf((acc0.x + acc0.y) + (acc1.x + acc1.y));
        if (act) bp_sh[t][lane] = (unsigned char)bi;
        vit = best + emv;
    };

    // ---- t = 0: fwd init (peeled, exact) + vit step 0 ----
    float em0 = act ? fb[lane] : 0.0f;
    alpha = em0 + tstart;          // only prev=START contributes at t=0
    {
        wbuf[0][lane] = vit;
        __syncthreads();
        const float4* ww = (const float4*)wbuf[0];
        float bs[12]; int ib[12];
        #pragma unroll
        for (int g = 0; g < KS / 4; ++g) {
            float4 w = ww[g];
            v2f ta = {Trow[4 * g + 0], Trow[4 * g + 1]};
            v2f tc = {Trow[4 * g + 2], Trow[4 * g + 3]};
            v2f wa = {w.x, w.y}, wb = {w.z, w.w};
            v2f sa = wa + ta;
            v2f sb = wb + tc;
            float m01 = fmaxf(sa.x, sa.y); int i01 = (sa.y > sa.x) ? 4 * g + 1 : 4 * g + 0;
            float m23 = fmaxf(sb.x, sb.y); int i23 = (sb.y > sb.x) ? 4 * g + 3 : 4 * g + 2;
            bs[g] = fmaxf(m01, m23);       ib[g] = (m23 > m01) ? i23 : i01;
        }
        #pragma unroll
        for (int st = 0; st < 6; ++st) {
            float a = bs[2 * st], c2 = bs[2 * st + 1];
            int ia = ib[2 * st], ic = ib[2 * st + 1];
            bs[st] = fmaxf(a, c2); ib[st] = (c2 > a) ? ic : ia;
        }
        #pragma unroll
        for (int st = 0; st < 3; ++st) {
            float a = bs[2 * st], c2 = bs[2 * st + 1];
            int ia = ib[2 * st], ic = ib[2 * st + 1];
            bs[st] = fmaxf(a, c2); ib[st] = (c2 > a) ? ic : ia;
        }
        float best = fmaxf(bs[0], bs[1]);
        int   bi   = (bs[1] > bs[0]) ? ib[1] : ib[0];
        bi   = (bs[2] > best) ? ib[2] : bi;
        best = fmaxf(best, bs[2]);
        if (act) bp_sh[0][lane] = (unsigned char)bi;
        vit = best + em0;
    }

    // ---- steps t=1..511 with 8-deep emission prefetch; 511 = 63*8 + 7 ----
    float em[PF];
    #pragma unroll
    for (int j = 0; j < PF; ++j)
        em[j] = act ? fb[(1 + j) * KS + lane] : 0.0f;
    for (int c = 0; c < 63; ++c) {
        const int t0 = 1 + c * PF;
        float em_n[PF];
        #pragma unroll
        for (int j = 0; j < PF; ++j) {
            int tf = t0 + PF + j;
            em_n[j] = (act && tf < TLEN) ? fb[tf * KS + lane] : 0.0f;
        }
        #pragma unroll
        for (int j = 0; j < PF; ++j) cstep(em[j], t0 + j);
        #pragma unroll
        for (int j = 0; j < PF; ++j) em[j] = em_n[j];
    }
    #pragma unroll
    for (int j = 0; j < 7; ++j) cstep(em[j], 505 + j);

    // ---- terminals ----
    float tstop = act ? trans[STOP_S * KS + lane] : NEGV;
    if (lane == STOP_S) tstop = NEGV;

    // logZ = LSE(alpha + trans[STOP])
    float z = alpha + tstop;
    float mz = z;
    #pragma unroll
    for (int off = 32; off; off >>= 1)
        mz = fmaxf(mz, __shfl_xor(mz, off, 64));
    float se = __expf(z - mz);
    #pragma unroll
    for (int off = 32; off; off >>= 1)
        se += __shfl_xor(se, off, 64);
    float logZ = mz + __logf(se);

    // viterbi terminal argmax (first-index tie-break)
    float term = act ? (vit + tstop) : -3.0e38f;
    float bv = term;
    int   bidx = act ? lane : 9999;
    #pragma unroll
    for (int off = 32; off; off >>= 1) {
        float ov = __shfl_xor(bv, off, 64);
        int   oi = __shfl_xor(bidx, off, 64);
        if (ov > bv || (ov == bv && oi < bidx)) { bv = ov; bidx = oi; }
    }

    // gold score: 64 lanes, 8 timesteps each
    float g = 0.0f;
    for (int t = lane; t < TLEN; t += 64) {
        int tg = tb[t];
        int pg = (t == 0) ? START_S : tb[t - 1];
        g += fb[t * KS + tg] + trans[tg * KS + pg];
    }
    #pragma unroll
    for (int off = 32; off; off >>= 1)
        g += __shfl_xor(g, off, 64);
    g += trans[STOP_S * KS + tb[TLEN - 1]];

    if (lane == 0) {
        out[b]      = logZ - g;
        out[BN + b] = bv;
    }

    // ---- backtrace: serial LDS walk (uniform broadcast reads) ----
    int tag = bidx;
    for (int t = TLEN - 1; t >= 0; --t) {
        if (lane == 0) path_sh[t] = (unsigned char)tag;
        tag = bp_sh[t][tag];
    }
    __syncthreads();
    float* pout = out + 2 * BN + (size_t)b * TLEN;
    for (int t = lane; t < TLEN; t += 64)
        pout[t] = (float)path_sh[t];
}

extern "C" void kernel_launch(void* const* d_in, const int* in_sizes, int n_in,
                              void* d_out, int out_size, void* d_ws, size_t ws_size,
                              hipStream_t stream) {
    const float* feats = (const float*)d_in[0];
    const float* trans = (const float*)d_in[1];
    const int*   tags  = (const int*)d_in[2];
    float*       out   = (float*)d_out;
    (void)in_sizes; (void)n_in; (void)out_size; (void)d_ws; (void)ws_size;
    crf_fused<<<dim3(BN), dim3(64), 0, stream>>>(feats, trans, tags, out);
}